// Round 1
// baseline (1483.465 us; speedup 1.0000x reference)
//
#include <hip/hip_runtime.h>
#include <cstdint>
#include <cstddef>

// ---- problem constants (from reference) ----
static constexpr int BATCH = 32;
static constexpr int CIN   = 3;
static constexpr int HIN   = 224, WIN = 224;
static constexpr int COUT  = 64;
static constexpr int HOUT  = 56, WOUT = 56;
static constexpr int NEXP  = 8;
static constexpr int KS    = 7;
static constexpr float LN_EPS_F = 1e-6f;

// ws layout (in floats):
//   [0 .. 95]     gate_inp  (32*3)
//   [128 .. 255]  gate_info (32 x float4: g1, g2, e1_bits, e2_bits)
//   [256 .. ]     padded weights pw[9*64][21][8]  (expert 0..7, slot 8 = shared)
static constexpr int WS_GATEINP  = 0;
static constexpr int WS_GATEINFO = 128;
static constexpr int WS_PW       = 256;
static constexpr int PW_FLOATS   = 9 * 64 * 21 * 8; // 96768

// ---------------- kernel 1: gate_inp = mean_{H,W}(x)  [32*3] ----------------
__global__ __launch_bounds__(256) void k_gate_mean(const float* __restrict__ x,
                                                   float* __restrict__ gate_inp) {
  const int bc = blockIdx.x; // 0..95  (b*3 + c)
  const float* p = x + (size_t)bc * (HIN * WIN);
  float s = 0.f;
  for (int i = threadIdx.x; i < HIN * WIN; i += 256) s += p[i];
  __shared__ float red[256];
  red[threadIdx.x] = s;
  __syncthreads();
  for (int off = 128; off > 0; off >>= 1) {
    if ((int)threadIdx.x < off) red[threadIdx.x] += red[threadIdx.x + off];
    __syncthreads();
  }
  if (threadIdx.x == 0) gate_inp[bc] = red[0] * (1.f / (float)(HIN * WIN));
}

// ---------------- kernel 2: gating (top-2 softmax) + aux loss ----------------
__global__ __launch_bounds__(256) void k_gating(const float* __restrict__ gate_inp,
                                                const float* __restrict__ w_gate, // [3][8]
                                                float* __restrict__ gate_info,    // 32 x float4
                                                float* __restrict__ loss_out) {
  __shared__ float gates[BATCH][NEXP];
  __shared__ float simp[NEXP], slod[NEXP];
  const int t = threadIdx.x;
  if (t < BATCH * NEXP) (&gates[0][0])[t] = 0.f;
  __syncthreads();
  if (t < BATCH) {
    const float gi0 = gate_inp[t * 3 + 0];
    const float gi1 = gate_inp[t * 3 + 1];
    const float gi2 = gate_inp[t * 3 + 2];
    float best1 = -1e30f, best2 = -1e30f;
    int i1 = 0, i2 = 0;
    for (int e = 0; e < NEXP; ++e) {
      const float lg = gi0 * w_gate[e] + gi1 * w_gate[8 + e] + gi2 * w_gate[16 + e];
      if (lg > best1) { best2 = best1; i2 = i1; best1 = lg; i1 = e; }
      else if (lg > best2) { best2 = lg; i2 = e; }
    }
    // stable softmax over the two top values
    const float e21 = expf(best2 - best1);
    const float den = 1.f + e21;
    const float g1 = 1.f / den;
    const float g2 = e21 / den;
    gates[t][i1] = g1;
    gates[t][i2] = g2;
    float4 info;
    info.x = g1; info.y = g2;
    info.z = __int_as_float(i1); info.w = __int_as_float(i2);
    reinterpret_cast<float4*>(gate_info)[t] = info;
  }
  __syncthreads();
  if (t < NEXP) {
    float si = 0.f, sl = 0.f;
    for (int b = 0; b < BATCH; ++b) {
      const float g = gates[b][t];
      si += g;
      if (g > 0.f) sl += 1.f;
    }
    simp[t] = si; slod[t] = sl;
  }
  __syncthreads();
  if (t == 0) {
    float mi = 0.f, ml = 0.f;
    for (int e = 0; e < NEXP; ++e) { mi += simp[e]; ml += slod[e]; }
    mi *= (1.f / NEXP); ml *= (1.f / NEXP);
    float vi = 0.f, vl = 0.f;
    for (int e = 0; e < NEXP; ++e) {
      const float di = simp[e] - mi; vi += di * di;
      const float dl = slod[e] - ml; vl += dl * dl;
    }
    vi *= (1.f / (NEXP - 1)); vl *= (1.f / (NEXP - 1)); // ddof=1
    const float loss = 0.01f * (vi / (mi * mi + 1e-10f) + vl / (ml * ml + 1e-10f));
    loss_out[0] = loss;
  }
}

// ---------------- kernel 3: repack weights into kw-padded rows ----------------
// pw[(e*64+co)][row(=ci*7+kh)][8], slot e==8 is the shared expert; pw[...][7]=0
__global__ __launch_bounds__(256) void k_repack(const float* __restrict__ eW,
                                                const float* __restrict__ sW,
                                                float* __restrict__ pw) {
  const int idx = blockIdx.x * 256 + threadIdx.x;
  if (idx >= PW_FLOATS) return;
  const int kw  = idx & 7;
  const int row = (idx >> 3) % 21;
  const int coe = idx / (21 * 8); // e*64 + co, e in [0,9)
  const int e   = coe >> 6;
  const int co  = coe & 63;
  float v = 0.f;
  if (kw < 7) {
    v = (e < 8) ? eW[(size_t)coe * 147 + row * 7 + kw]
                : sW[(size_t)co  * 147 + row * 7 + kw];
  }
  pw[idx] = v;
}

// ---------------- kernel 4: main conv + LN + gated combine ----------------
// 1 wave = 1 output pixel, lane = output channel. 4 waves/block (adjacent ow).
__global__ __launch_bounds__(256) void k_main(
    const float* __restrict__ x,
    const float* __restrict__ eW, const float* __restrict__ sW,
    const float* __restrict__ eB, const float* __restrict__ sB,
    const float* __restrict__ elnw, const float* __restrict__ elnb,
    const float* __restrict__ slnw, const float* __restrict__ slnb,
    const float* __restrict__ ws, int use_pad,
    float* __restrict__ out) {
  const int lane = threadIdx.x & 63;
  const int wave = threadIdx.x >> 6;
  const int pix  = blockIdx.x * 4 + wave; // 0 .. 32*3136-1
  const int b    = pix / (HOUT * WOUT);
  const int p    = pix - b * (HOUT * WOUT);
  const int oh   = p / WOUT;
  const int ow   = p - oh * WOUT;

  const float4 gi = *reinterpret_cast<const float4*>(ws + WS_GATEINFO + b * 4);
  const float g1 = gi.x, g2 = gi.y;
  const int e1 = __float_as_int(gi.z), e2 = __float_as_int(gi.w);

  const float* __restrict__ pw = ws + WS_PW;

  float acc1 = 0.f, acc2 = 0.f, accS = 0.f;
  const float* xb = x + (size_t)b * (CIN * HIN * WIN);
  const int iw0 = ow * 4 - 3;
  const int ih0 = oh * 4 - 3;

  for (int ci = 0; ci < CIN; ++ci) {
    #pragma unroll
    for (int kh = 0; kh < KS; ++kh) {
      const int ih = ih0 + kh;
      if ((unsigned)ih >= (unsigned)HIN) continue; // wave-uniform branch
      const float* xrow = xb + (size_t)(ci * HIN + ih) * WIN;
      float xr[7];
      #pragma unroll
      for (int kw = 0; kw < 7; ++kw) {
        const int iw = iw0 + kw;
        xr[kw] = ((unsigned)iw < (unsigned)WIN) ? xrow[iw] : 0.f;
      }
      const int row = ci * KS + kh;
      if (use_pad) {
        const float4* w1 = reinterpret_cast<const float4*>(pw + ((size_t)(e1 * 64 + lane) * 21 + row) * 8);
        const float4* w2 = reinterpret_cast<const float4*>(pw + ((size_t)(e2 * 64 + lane) * 21 + row) * 8);
        const float4* wS = reinterpret_cast<const float4*>(pw + ((size_t)(8  * 64 + lane) * 21 + row) * 8);
        const float4 a1 = w1[0], c1 = w1[1];
        const float4 a2 = w2[0], c2 = w2[1];
        const float4 aS = wS[0], cS = wS[1];
        acc1 += xr[0]*a1.x + xr[1]*a1.y + xr[2]*a1.z + xr[3]*a1.w + xr[4]*c1.x + xr[5]*c1.y + xr[6]*c1.z;
        acc2 += xr[0]*a2.x + xr[1]*a2.y + xr[2]*a2.z + xr[3]*a2.w + xr[4]*c2.x + xr[5]*c2.y + xr[6]*c2.z;
        accS += xr[0]*aS.x + xr[1]*aS.y + xr[2]*aS.z + xr[3]*aS.w + xr[4]*cS.x + xr[5]*cS.y + xr[6]*cS.z;
      } else {
        const float* w1 = eW + ((size_t)(e1 * 64 + lane) * CIN + ci) * 49 + kh * 7;
        const float* w2 = eW + ((size_t)(e2 * 64 + lane) * CIN + ci) * 49 + kh * 7;
        const float* wS = sW + ((size_t)lane * CIN + ci) * 49 + kh * 7;
        #pragma unroll
        for (int kw = 0; kw < 7; ++kw) {
          acc1 += xr[kw] * w1[kw];
          acc2 += xr[kw] * w2[kw];
          accS += xr[kw] * wS[kw];
        }
      }
    }
  }

  float v1 = acc1 + eB[e1 * 64 + lane];
  float v2 = acc2 + eB[e2 * 64 + lane];
  float vS = accS + sB[lane];

  auto wsum = [](float v) {
    #pragma unroll
    for (int o = 32; o > 0; o >>= 1) v += __shfl_xor(v, o, 64);
    return v;
  };

  const float u1 = wsum(v1) * (1.f / 64.f);
  const float u2 = wsum(v2) * (1.f / 64.f);
  const float uS = wsum(vS) * (1.f / 64.f);
  const float d1 = v1 - u1, d2 = v2 - u2, dS = vS - uS;
  const float s1 = wsum(d1 * d1) * (1.f / 64.f);
  const float s2 = wsum(d2 * d2) * (1.f / 64.f);
  const float sS = wsum(dS * dS) * (1.f / 64.f);

  const float o1 = elnw[e1 * 64 + lane] * (d1 * rsqrtf(s1 + LN_EPS_F)) + elnb[e1 * 64 + lane];
  const float o2 = elnw[e2 * 64 + lane] * (d2 * rsqrtf(s2 + LN_EPS_F)) + elnb[e2 * 64 + lane];
  const float oS = slnw[lane] * (dS * rsqrtf(sS + LN_EPS_F)) + slnb[lane];

  const float r = g1 * o1 + g2 * o2 + oS;
  out[((size_t)(b * COUT + lane) * HOUT + oh) * WOUT + ow] = r;
}

// ---------------- launch ----------------
extern "C" void kernel_launch(void* const* d_in, const int* in_sizes, int n_in,
                              void* d_out, int out_size, void* d_ws, size_t ws_size,
                              hipStream_t stream) {
  const float* x    = (const float*)d_in[0];
  const float* eW   = (const float*)d_in[1];
  const float* eB   = (const float*)d_in[2];
  const float* elnw = (const float*)d_in[3];
  const float* elnb = (const float*)d_in[4];
  const float* sW   = (const float*)d_in[5];
  const float* sB   = (const float*)d_in[6];
  const float* slnw = (const float*)d_in[7];
  const float* slnb = (const float*)d_in[8];
  const float* wg   = (const float*)d_in[9];
  float* out = (float*)d_out;
  float* ws  = (float*)d_ws;

  const size_t need = (size_t)(WS_PW + PW_FLOATS) * sizeof(float);
  const int use_pad = (ws_size >= need) ? 1 : 0;

  float* loss_ptr = out + (size_t)BATCH * COUT * HOUT * WOUT; // element 6422528

  k_gate_mean<<<BATCH * CIN, 256, 0, stream>>>(x, ws + WS_GATEINP);
  k_gating<<<1, 256, 0, stream>>>(ws + WS_GATEINP, wg, ws + WS_GATEINFO, loss_ptr);
  if (use_pad) {
    k_repack<<<(PW_FLOATS + 255) / 256, 256, 0, stream>>>(eW, sW, ws + WS_PW);
  }
  const int nblocks = BATCH * HOUT * WOUT / 4; // 25088
  k_main<<<nblocks, 256, 0, stream>>>(x, eW, sW, eB, sB, elnw, elnb, slnw, slnb,
                                      ws, use_pad, out);
}

// Round 2
// 444.701 us; speedup vs baseline: 3.3359x; 3.3359x over previous
//
#include <hip/hip_runtime.h>
#include <cstdint>
#include <cstddef>

// ---- problem constants (from reference) ----
static constexpr int BATCH = 32;
static constexpr int CIN   = 3;
static constexpr int HIN   = 224, WIN = 224;
static constexpr int COUT  = 64;
static constexpr int HOUT  = 56, WOUT = 56;
static constexpr int NPIX  = HOUT * WOUT;       // 3136 = 49 * 64
static constexpr int NEXP  = 8;
static constexpr int KS    = 7;
static constexpr int KVOL  = CIN * KS * KS;     // 147
static constexpr float LN_EPS_F = 1e-6f;

// ws layout (in floats):
//   [0 .. 95]     gate_inp  (32*3)
//   [128 .. 255]  gate_info (32 x float4: g1, g2, e1_bits, e2_bits)
static constexpr int WS_GATEINP  = 0;
static constexpr int WS_GATEINFO = 128;

// ---------------- kernel 1: gate_inp = mean_{H,W}(x)  [32*3] ----------------
__global__ __launch_bounds__(256) void k_gate_mean(const float* __restrict__ x,
                                                   float* __restrict__ gate_inp) {
  const int bc = blockIdx.x; // 0..95  (b*3 + c)
  const float* p = x + (size_t)bc * (HIN * WIN);
  float s = 0.f;
  // vectorized: 224*224 = 50176 = 12544 float4
  const float4* p4 = reinterpret_cast<const float4*>(p);
  for (int i = threadIdx.x; i < (HIN * WIN) / 4; i += 256) {
    const float4 v = p4[i];
    s += v.x + v.y + v.z + v.w;
  }
  __shared__ float red[256];
  red[threadIdx.x] = s;
  __syncthreads();
  for (int off = 128; off > 0; off >>= 1) {
    if ((int)threadIdx.x < off) red[threadIdx.x] += red[threadIdx.x + off];
    __syncthreads();
  }
  if (threadIdx.x == 0) gate_inp[bc] = red[0] * (1.f / (float)(HIN * WIN));
}

// ---------------- kernel 2: gating (top-2 softmax) + aux loss ----------------
__global__ __launch_bounds__(256) void k_gating(const float* __restrict__ gate_inp,
                                                const float* __restrict__ w_gate, // [3][8]
                                                float* __restrict__ gate_info,    // 32 x float4
                                                float* __restrict__ loss_out) {
  __shared__ float gates[BATCH][NEXP];
  __shared__ float simp[NEXP], slod[NEXP];
  const int t = threadIdx.x;
  if (t < BATCH * NEXP) (&gates[0][0])[t] = 0.f;
  __syncthreads();
  if (t < BATCH) {
    const float gi0 = gate_inp[t * 3 + 0];
    const float gi1 = gate_inp[t * 3 + 1];
    const float gi2 = gate_inp[t * 3 + 2];
    float best1 = -1e30f, best2 = -1e30f;
    int i1 = 0, i2 = 0;
    for (int e = 0; e < NEXP; ++e) {
      const float lg = gi0 * w_gate[e] + gi1 * w_gate[8 + e] + gi2 * w_gate[16 + e];
      if (lg > best1) { best2 = best1; i2 = i1; best1 = lg; i1 = e; }
      else if (lg > best2) { best2 = lg; i2 = e; }
    }
    const float e21 = expf(best2 - best1);
    const float den = 1.f + e21;
    const float g1 = 1.f / den;
    const float g2 = e21 / den;
    gates[t][i1] = g1;
    gates[t][i2] = g2;
    float4 info;
    info.x = g1; info.y = g2;
    info.z = __int_as_float(i1); info.w = __int_as_float(i2);
    reinterpret_cast<float4*>(gate_info)[t] = info;
  }
  __syncthreads();
  if (t < NEXP) {
    float si = 0.f, sl = 0.f;
    for (int b = 0; b < BATCH; ++b) {
      const float g = gates[b][t];
      si += g;
      if (g > 0.f) sl += 1.f;
    }
    simp[t] = si; slod[t] = sl;
  }
  __syncthreads();
  if (t == 0) {
    float mi = 0.f, ml = 0.f;
    for (int e = 0; e < NEXP; ++e) { mi += simp[e]; ml += slod[e]; }
    mi *= (1.f / NEXP); ml *= (1.f / NEXP);
    float vi = 0.f, vl = 0.f;
    for (int e = 0; e < NEXP; ++e) {
      const float di = simp[e] - mi; vi += di * di;
      const float dl = slod[e] - ml; vl += dl * dl;
    }
    vi *= (1.f / (NEXP - 1)); vl *= (1.f / (NEXP - 1)); // ddof=1
    const float loss = 0.01f * (vi / (mi * mi + 1e-10f) + vl / (ml * ml + 1e-10f));
    loss_out[0] = loss;
  }
}

// ---------------- kernel 3: main conv + LN + gated combine ----------------
// 1 wave per block; lane = pixel (64 consecutive pixels of one image).
// Loop co: weights are wave-uniform -> scalar loads; inner product over the
// per-lane register patch. Two passes: (A) LN stats, (B) recompute + combine.
__global__ __launch_bounds__(64) void k_main(
    const float* __restrict__ x,
    const float* __restrict__ eW, const float* __restrict__ sW,
    const float* __restrict__ eB, const float* __restrict__ sB,
    const float* __restrict__ elnw, const float* __restrict__ elnb,
    const float* __restrict__ slnw, const float* __restrict__ slnb,
    const float* __restrict__ gate_info,
    float* __restrict__ out) {
  const int lane = threadIdx.x;           // 0..63
  const int b    = blockIdx.x / (NPIX / 64);   // image
  const int pblk = blockIdx.x % (NPIX / 64);   // pixel block within image
  const int p    = pblk * 64 + lane;           // 0..3135
  const int oh   = p / WOUT;
  const int ow   = p - oh * WOUT;

  // gate info (block-uniform)
  const float4 gi = *reinterpret_cast<const float4*>(gate_info + b * 4);
  const float g1 = gi.x, g2 = gi.y;
  const int e1 = __builtin_amdgcn_readfirstlane(__float_as_int(gi.z));
  const int e2 = __builtin_amdgcn_readfirstlane(__float_as_int(gi.w));

  // uniform weight bases
  const float* __restrict__ w1base = eW + (size_t)(e1 * COUT) * KVOL;
  const float* __restrict__ w2base = eW + (size_t)(e2 * COUT) * KVOL;
  const float* __restrict__ wSbase = sW;

  // ---- load the per-lane input patch into registers (147 VGPRs) ----
  float patch[KVOL];
  const float* xb = x + (size_t)b * (CIN * HIN * WIN);
  const int ih0 = oh * 4 - 3;
  const int iw0 = ow * 4 - 3;
  #pragma unroll
  for (int ci = 0; ci < CIN; ++ci) {
    #pragma unroll
    for (int kh = 0; kh < KS; ++kh) {
      const int ih = ih0 + kh;
      const float* xrow = xb + (size_t)(ci * HIN + ih) * WIN;
      #pragma unroll
      for (int kw = 0; kw < KS; ++kw) {
        const int iw = iw0 + kw;
        const bool valid = ((unsigned)ih < (unsigned)HIN) & ((unsigned)iw < (unsigned)WIN);
        patch[ci * 49 + kh * 7 + kw] = valid ? xrow[iw] : 0.f;
      }
    }
  }

  // ---- pass A: LN statistics per expert (per lane = per pixel) ----
  float s1 = 0.f, q1 = 0.f, s2 = 0.f, q2 = 0.f, sS = 0.f, qS = 0.f;
  for (int co = 0; co < COUT; ++co) {
    const float* __restrict__ w1 = w1base + (size_t)co * KVOL;
    const float* __restrict__ w2 = w2base + (size_t)co * KVOL;
    const float* __restrict__ wS = wSbase + (size_t)co * KVOL;
    float a1 = 0.f, a2 = 0.f, aS = 0.f;
    #pragma unroll
    for (int k = 0; k < KVOL; ++k) {
      a1 += patch[k] * w1[k];
      a2 += patch[k] * w2[k];
      aS += patch[k] * wS[k];
    }
    const float y1 = a1 + eB[e1 * COUT + co];
    const float y2 = a2 + eB[e2 * COUT + co];
    const float yS = aS + sB[co];
    s1 += y1; q1 += y1 * y1;
    s2 += y2; q2 += y2 * y2;
    sS += yS; qS += yS * yS;
  }

  const float u1 = s1 * (1.f / 64.f);
  const float u2 = s2 * (1.f / 64.f);
  const float uS = sS * (1.f / 64.f);
  const float v1 = q1 * (1.f / 64.f) - u1 * u1;
  const float v2 = q2 * (1.f / 64.f) - u2 * u2;
  const float vS = qS * (1.f / 64.f) - uS * uS;
  const float r1 = g1 * rsqrtf(v1 + LN_EPS_F);
  const float r2 = g2 * rsqrtf(v2 + LN_EPS_F);
  const float rS = rsqrtf(vS + LN_EPS_F);

  // ---- pass B: recompute conv, apply LN + gated combine, store ----
  float* outb = out + (size_t)b * (COUT * NPIX) + p;
  for (int co = 0; co < COUT; ++co) {
    const float* __restrict__ w1 = w1base + (size_t)co * KVOL;
    const float* __restrict__ w2 = w2base + (size_t)co * KVOL;
    const float* __restrict__ wS = wSbase + (size_t)co * KVOL;
    float a1 = 0.f, a2 = 0.f, aS = 0.f;
    #pragma unroll
    for (int k = 0; k < KVOL; ++k) {
      a1 += patch[k] * w1[k];
      a2 += patch[k] * w2[k];
      aS += patch[k] * wS[k];
    }
    const float y1 = a1 + eB[e1 * COUT + co];
    const float y2 = a2 + eB[e2 * COUT + co];
    const float yS = aS + sB[co];
    const float o = r1 * elnw[e1 * COUT + co] * (y1 - u1) + g1 * elnb[e1 * COUT + co]
                  + r2 * elnw[e2 * COUT + co] * (y2 - u2) + g2 * elnb[e2 * COUT + co]
                  + rS * slnw[co] * (yS - uS) + slnb[co];
    outb[(size_t)co * NPIX] = o;
  }
}

// ---------------- launch ----------------
extern "C" void kernel_launch(void* const* d_in, const int* in_sizes, int n_in,
                              void* d_out, int out_size, void* d_ws, size_t ws_size,
                              hipStream_t stream) {
  const float* x    = (const float*)d_in[0];
  const float* eW   = (const float*)d_in[1];
  const float* eB   = (const float*)d_in[2];
  const float* elnw = (const float*)d_in[3];
  const float* elnb = (const float*)d_in[4];
  const float* sW   = (const float*)d_in[5];
  const float* sB   = (const float*)d_in[6];
  const float* slnw = (const float*)d_in[7];
  const float* slnb = (const float*)d_in[8];
  const float* wg   = (const float*)d_in[9];
  float* out = (float*)d_out;
  float* ws  = (float*)d_ws;

  float* loss_ptr = out + (size_t)BATCH * COUT * NPIX; // element 6422528

  k_gate_mean<<<BATCH * CIN, 256, 0, stream>>>(x, ws + WS_GATEINP);
  k_gating<<<1, 256, 0, stream>>>(ws + WS_GATEINP, wg, ws + WS_GATEINFO, loss_ptr);
  const int nblocks = BATCH * (NPIX / 64); // 32 * 49 = 1568
  k_main<<<nblocks, 64, 0, stream>>>(x, eW, sW, eB, sB, elnw, elnb, slnw, slnb,
                                     ws + WS_GATEINFO, out);
}

// Round 3
// 72.892 us; speedup vs baseline: 20.3517x; 6.1009x over previous
//
#include <hip/hip_runtime.h>
#include <cstdint>
#include <cstddef>

// ---- problem constants ----
static constexpr int BATCH = 32;
static constexpr int CIN   = 3;
static constexpr int HIN   = 224, WIN = 224;
static constexpr int COUT  = 64;
static constexpr int HOUT  = 56, WOUT = 56;
static constexpr int NPIX  = HOUT * WOUT;     // 3136 = 49*64
static constexpr int NEXP  = 8;
static constexpr int KS    = 7;
static constexpr int KVOL  = CIN * KS * KS;   // 147
static constexpr int KPAD  = 160;             // 5 K-steps of 32
static constexpr int PSTR  = 168;             // LDS row stride (bf16 elems) for bank spread
static constexpr float LN_EPS_F = 1e-6f;

typedef __bf16 bf16x8 __attribute__((ext_vector_type(8)));
typedef float  f32x4  __attribute__((ext_vector_type(4)));

// ---- device-global scratch (rewritten every launch; no ws_size dependence) ----
__device__ __align__(16) ushort g_pw[9 * COUT * KPAD];  // bf16 weights, slot 8 = shared
__device__ float  g_gateinp[BATCH * CIN];
__device__ float4 g_gateinfo[BATCH];                    // g1, g2, e1_bits, e2_bits

__device__ __forceinline__ ushort f2bf(float f) {
  uint u = __float_as_uint(f);
  uint r = (u + 0x7FFFu + ((u >> 16) & 1u)) >> 16;      // RNE
  return (ushort)r;
}

// ---------------- kernel 1: gate_inp = mean_{H,W}(x) ----------------
__global__ __launch_bounds__(256) void k_gate_mean(const float* __restrict__ x) {
  const int bc = blockIdx.x; // 0..95
  const float4* p4 = reinterpret_cast<const float4*>(x + (size_t)bc * (HIN * WIN));
  float s = 0.f;
  for (int i = threadIdx.x; i < (HIN * WIN) / 4; i += 256) {
    const float4 v = p4[i];
    s += v.x + v.y + v.z + v.w;
  }
  __shared__ float red[256];
  red[threadIdx.x] = s;
  __syncthreads();
  for (int off = 128; off > 0; off >>= 1) {
    if ((int)threadIdx.x < off) red[threadIdx.x] += red[threadIdx.x + off];
    __syncthreads();
  }
  if (threadIdx.x == 0) g_gateinp[bc] = red[0] * (1.f / (float)(HIN * WIN));
}

// ---------------- kernel 2: gating + aux loss ----------------
__global__ __launch_bounds__(256) void k_gating(const float* __restrict__ w_gate,
                                                float* __restrict__ loss_out) {
  __shared__ float gates[BATCH][NEXP];
  __shared__ float simp[NEXP], slod[NEXP];
  const int t = threadIdx.x;
  if (t < BATCH * NEXP) (&gates[0][0])[t] = 0.f;
  __syncthreads();
  if (t < BATCH) {
    const float gi0 = g_gateinp[t * 3 + 0];
    const float gi1 = g_gateinp[t * 3 + 1];
    const float gi2 = g_gateinp[t * 3 + 2];
    float best1 = -1e30f, best2 = -1e30f;
    int i1 = 0, i2 = 0;
    for (int e = 0; e < NEXP; ++e) {
      const float lg = gi0 * w_gate[e] + gi1 * w_gate[8 + e] + gi2 * w_gate[16 + e];
      if (lg > best1) { best2 = best1; i2 = i1; best1 = lg; i1 = e; }
      else if (lg > best2) { best2 = lg; i2 = e; }
    }
    const float e21 = expf(best2 - best1);
    const float den = 1.f + e21;
    gates[t][i1] = 1.f / den;
    gates[t][i2] = e21 / den;
    float4 info;
    info.x = 1.f / den; info.y = e21 / den;
    info.z = __int_as_float(i1); info.w = __int_as_float(i2);
    g_gateinfo[t] = info;
  }
  __syncthreads();
  if (t < NEXP) {
    float si = 0.f, sl = 0.f;
    for (int b = 0; b < BATCH; ++b) {
      const float g = gates[b][t];
      si += g;
      if (g > 0.f) sl += 1.f;
    }
    simp[t] = si; slod[t] = sl;
  }
  __syncthreads();
  if (t == 0) {
    float mi = 0.f, ml = 0.f;
    for (int e = 0; e < NEXP; ++e) { mi += simp[e]; ml += slod[e]; }
    mi *= (1.f / NEXP); ml *= (1.f / NEXP);
    float vi = 0.f, vl = 0.f;
    for (int e = 0; e < NEXP; ++e) {
      const float di = simp[e] - mi; vi += di * di;
      const float dl = slod[e] - ml; vl += dl * dl;
    }
    vi *= (1.f / (NEXP - 1)); vl *= (1.f / (NEXP - 1));
    loss_out[0] = 0.01f * (vi / (mi * mi + 1e-10f) + vl / (ml * ml + 1e-10f));
  }
}

// ---------------- kernel 3: repack weights -> bf16 [9][64][160] ----------------
__global__ __launch_bounds__(256) void k_repack(const float* __restrict__ eW,
                                                const float* __restrict__ sW) {
  const int idx = blockIdx.x * 256 + threadIdx.x;
  if (idx >= 9 * COUT * KPAD) return;
  const int k   = idx % KPAD;
  const int coe = idx / KPAD;   // e*64 + co
  const int e   = coe >> 6;
  const int co  = coe & 63;
  float v = 0.f;
  if (k < KVOL) {
    v = (e < 8) ? eW[(size_t)coe * KVOL + k] : sW[(size_t)co * KVOL + k];
  }
  g_pw[idx] = f2bf(v);
}

// ---------------- kernel 4: MFMA conv + LN + gated combine ----------------
// Block: 1 image x 64 pixels, 4 waves. Wave w owns co slice [16w, 16w+16).
__global__ __launch_bounds__(256) void k_main(
    const float* __restrict__ x,
    const float* __restrict__ eB, const float* __restrict__ sB,
    const float* __restrict__ elnw, const float* __restrict__ elnb,
    const float* __restrict__ slnw, const float* __restrict__ slnb,
    float* __restrict__ out) {
  __shared__ __align__(16) ushort Plds[64 * PSTR];      // im2col tile, pixel-major (B^T)
  __shared__ float2 Sstats[4 * 3 * 4 * 16];             // [wave][expert][cb][col]

  const int tid  = threadIdx.x;
  const int lane = tid & 63;
  const int w    = tid >> 6;
  const int b    = blockIdx.x / (NPIX / 64);
  const int t    = blockIdx.x % (NPIX / 64);

  // ---- gate info (block-uniform) ----
  const float4 gi = g_gateinfo[b];
  const float g1 = gi.x, g2 = gi.y;
  const int e1 = __builtin_amdgcn_readfirstlane(__float_as_int(gi.z));
  const int e2 = __builtin_amdgcn_readfirstlane(__float_as_int(gi.w));

  // ---- stage im2col tile: pixel = lane, rows split across waves ----
  {
    const int p  = lane;
    const int pg = t * 64 + p;
    const int oh = pg / WOUT;
    const int ow = pg - oh * WOUT;
    const int ih0 = oh * 4 - 3;
    const int iw0 = ow * 4 - 3;
    const float* xb = x + (size_t)b * (CIN * HIN * WIN);
    for (int r = w; r < 21; r += 4) {
      const int ci = r / 7;
      const int kh = r - ci * 7;
      const int ih = ih0 + kh;
      const bool ihok = (unsigned)ih < (unsigned)HIN;
      const float* xrow = xb + (size_t)(ci * HIN + ih) * WIN;
      #pragma unroll
      for (int kw = 0; kw < 7; ++kw) {
        const int iw = iw0 + kw;
        const float v = (ihok && (unsigned)iw < (unsigned)WIN) ? xrow[iw] : 0.f;
        Plds[p * PSTR + r * 7 + kw] = f2bf(v);
      }
    }
    if (w == 1) { // zero-pad k = 147..167 (disjoint bytes, no barrier needed)
      Plds[p * PSTR + KVOL] = 0;
      uint* z = reinterpret_cast<uint*>(&Plds[p * PSTR + KVOL + 1]);
      #pragma unroll
      for (int i = 0; i < 10; ++i) z[i] = 0u;
    }
  }

  // ---- A fragments: 16-co slice x 3 experts x 5 K-steps (registers) ----
  const int wbase = w * 16;
  const int arow  = wbase + (lane & 15);
  const int kcol  = (lane >> 4) * 8;
  bf16x8 afrag[3][5];
  const int eidx[3] = {e1, e2, 8};
  #pragma unroll
  for (int e = 0; e < 3; ++e) {
    #pragma unroll
    for (int ks = 0; ks < 5; ++ks) {
      const uint4 raw = *reinterpret_cast<const uint4*>(
          &g_pw[((size_t)(eidx[e] * COUT + arow)) * KPAD + ks * 32 + kcol]);
      afrag[e][ks] = __builtin_bit_cast(bf16x8, raw);
    }
  }

  __syncthreads();

  // ---- MFMA: acc[cb][e] = W_e · P  (16 co x 16 px per mfma) ----
  f32x4 acc[4][3];
  #pragma unroll
  for (int cb = 0; cb < 4; ++cb) {
    #pragma unroll
    for (int e = 0; e < 3; ++e) acc[cb][e] = (f32x4){0.f, 0.f, 0.f, 0.f};
  }
  #pragma unroll
  for (int cb = 0; cb < 4; ++cb) {
    bf16x8 bfrag[5];
    #pragma unroll
    for (int ks = 0; ks < 5; ++ks) {
      const uint4 raw = *reinterpret_cast<const uint4*>(
          &Plds[(cb * 16 + (lane & 15)) * PSTR + ks * 32 + kcol]);
      bfrag[ks] = __builtin_bit_cast(bf16x8, raw);
    }
    #pragma unroll
    for (int ks = 0; ks < 5; ++ks) {
      #pragma unroll
      for (int e = 0; e < 3; ++e) {
        acc[cb][e] = __builtin_amdgcn_mfma_f32_16x16x32_bf16(
            afrag[e][ks], bfrag[ks], acc[cb][e], 0, 0, 0);
      }
    }
  }

  // ---- bias, then per-pixel LN stats (sum, sumsq over co) ----
  const int co0 = wbase + (lane >> 4) * 4;  // 4 consecutive co per lane (rows)
  const int col = lane & 15;
  float4 bias[3];
  bias[0] = *reinterpret_cast<const float4*>(eB + e1 * COUT + co0);
  bias[1] = *reinterpret_cast<const float4*>(eB + e2 * COUT + co0);
  bias[2] = *reinterpret_cast<const float4*>(sB + co0);
  #pragma unroll
  for (int cb = 0; cb < 4; ++cb) {
    #pragma unroll
    for (int e = 0; e < 3; ++e) {
      acc[cb][e][0] += (&bias[e].x)[0];
      acc[cb][e][1] += (&bias[e].x)[1];
      acc[cb][e][2] += (&bias[e].x)[2];
      acc[cb][e][3] += (&bias[e].x)[3];
    }
  }
  #pragma unroll
  for (int cb = 0; cb < 4; ++cb) {
    #pragma unroll
    for (int e = 0; e < 3; ++e) {
      float s = acc[cb][e][0] + acc[cb][e][1] + acc[cb][e][2] + acc[cb][e][3];
      float q = acc[cb][e][0] * acc[cb][e][0] + acc[cb][e][1] * acc[cb][e][1]
              + acc[cb][e][2] * acc[cb][e][2] + acc[cb][e][3] * acc[cb][e][3];
      s += __shfl_xor(s, 16, 64); s += __shfl_xor(s, 32, 64);
      q += __shfl_xor(q, 16, 64); q += __shfl_xor(q, 32, 64);
      if (lane < 16) Sstats[((w * 3 + e) * 4 + cb) * 16 + col] = make_float2(s, q);
    }
  }
  __syncthreads();

  // ---- LN params per lane ----
  float4 lw[3], lb[3];
  lw[0] = *reinterpret_cast<const float4*>(elnw + e1 * COUT + co0);
  lw[1] = *reinterpret_cast<const float4*>(elnw + e2 * COUT + co0);
  lw[2] = *reinterpret_cast<const float4*>(slnw + co0);
  lb[0] = *reinterpret_cast<const float4*>(elnb + e1 * COUT + co0);
  lb[1] = *reinterpret_cast<const float4*>(elnb + e2 * COUT + co0);
  lb[2] = *reinterpret_cast<const float4*>(slnb + co0);
  const float ge[3] = {g1, g2, 1.f};

  float* outb = out + (size_t)b * (COUT * NPIX) + t * 64;
  #pragma unroll
  for (int cb = 0; cb < 4; ++cb) {
    float u[3], rr[3];
    #pragma unroll
    for (int e = 0; e < 3; ++e) {
      float s = 0.f, q = 0.f;
      #pragma unroll
      for (int ww = 0; ww < 4; ++ww) {
        const float2 sq = Sstats[((ww * 3 + e) * 4 + cb) * 16 + col];
        s += sq.x; q += sq.y;
      }
      u[e] = s * (1.f / 64.f);
      const float var = q * (1.f / 64.f) - u[e] * u[e];
      rr[e] = rsqrtf(var + LN_EPS_F);
    }
    #pragma unroll
    for (int reg = 0; reg < 4; ++reg) {
      float o = 0.f;
      #pragma unroll
      for (int e = 0; e < 3; ++e) {
        const float y = acc[cb][e][reg];
        o += ge[e] * ((&lw[e].x)[reg] * (y - u[e]) * rr[e] + (&lb[e].x)[reg]);
      }
      outb[(size_t)(co0 + reg) * NPIX + cb * 16 + col] = o;
    }
  }
}

// ---------------- launch ----------------
extern "C" void kernel_launch(void* const* d_in, const int* in_sizes, int n_in,
                              void* d_out, int out_size, void* d_ws, size_t ws_size,
                              hipStream_t stream) {
  const float* x    = (const float*)d_in[0];
  const float* eW   = (const float*)d_in[1];
  const float* eB   = (const float*)d_in[2];
  const float* elnw = (const float*)d_in[3];
  const float* elnb = (const float*)d_in[4];
  const float* sW   = (const float*)d_in[5];
  const float* sB   = (const float*)d_in[6];
  const float* slnw = (const float*)d_in[7];
  const float* slnb = (const float*)d_in[8];
  const float* wg   = (const float*)d_in[9];
  float* out = (float*)d_out;

  float* loss_ptr = out + (size_t)BATCH * COUT * NPIX;

  k_repack<<<(9 * COUT * KPAD + 255) / 256, 256, 0, stream>>>(eW, sW);
  k_gate_mean<<<BATCH * CIN, 256, 0, stream>>>(x);
  k_gating<<<1, 256, 0, stream>>>(wg, loss_ptr);
  k_main<<<BATCH * (NPIX / 64), 256, 0, stream>>>(x, eB, sB, elnw, elnb,
                                                  slnw, slnb, out);
}

// Round 4
// 68.516 us; speedup vs baseline: 21.6515x; 1.0639x over previous
//
#include <hip/hip_runtime.h>
#include <cstdint>
#include <cstddef>

// ---- problem constants ----
static constexpr int BATCH = 32;
static constexpr int CIN   = 3;
static constexpr int HIN   = 224, WIN = 224;
static constexpr int COUT  = 64;
static constexpr int HOUT  = 56, WOUT = 56;
static constexpr int NPIX  = HOUT * WOUT;     // 3136 = 49*64
static constexpr int NEXP  = 8;
static constexpr int KS    = 7;
static constexpr int KVOL  = CIN * KS * KS;   // 147
static constexpr int KPAD  = 160;             // 5 K-steps of 32
static constexpr int PSTR  = 168;             // im2col LDS row stride (bf16) — bank spread
static constexpr int RAWROWS = 33;            // 3 ci * 11 ih rows
static constexpr float LN_EPS_F = 1e-6f;

typedef __bf16 bf16x8 __attribute__((ext_vector_type(8)));
typedef float  f32x4  __attribute__((ext_vector_type(4)));

// ---- device-global scratch ----
__device__ __align__(16) ushort g_pw[9 * COUT * KPAD];  // bf16 weights, slot 8 = shared
__device__ float  g_gateinp[BATCH * CIN];
__device__ float4 g_gateinfo[BATCH];                    // g1, g2, e1_bits, e2_bits

__device__ __forceinline__ ushort f2bf(float f) {
  uint u = __float_as_uint(f);
  uint r = (u + 0x7FFFu + ((u >> 16) & 1u)) >> 16;      // RNE
  return (ushort)r;
}

// ---------------- kernel 1: fused gate_mean (blocks 0..95) + repack (96..455) ----
__global__ __launch_bounds__(256) void k_pre(const float* __restrict__ x,
                                             const float* __restrict__ eW,
                                             const float* __restrict__ sW) {
  const int bid = blockIdx.x;
  if (bid < BATCH * CIN) {
    // ---- gate_inp = mean_{H,W}(x) ----
    const float4* p4 = reinterpret_cast<const float4*>(x + (size_t)bid * (HIN * WIN));
    float s = 0.f;
    for (int i = threadIdx.x; i < (HIN * WIN) / 4; i += 256) {
      const float4 v = p4[i];
      s += v.x + v.y + v.z + v.w;
    }
    __shared__ float red[256];
    red[threadIdx.x] = s;
    __syncthreads();
    for (int off = 128; off > 0; off >>= 1) {
      if ((int)threadIdx.x < off) red[threadIdx.x] += red[threadIdx.x + off];
      __syncthreads();
    }
    if (threadIdx.x == 0) g_gateinp[bid] = red[0] * (1.f / (float)(HIN * WIN));
  } else {
    // ---- repack weights -> bf16 [9][64][160] ----
    const int idx = (bid - BATCH * CIN) * 256 + threadIdx.x;
    if (idx >= 9 * COUT * KPAD) return;
    const int k   = idx % KPAD;
    const int coe = idx / KPAD;   // e*64 + co
    const int e   = coe >> 6;
    const int co  = coe & 63;
    float v = 0.f;
    if (k < KVOL) {
      v = (e < 8) ? eW[(size_t)coe * KVOL + k] : sW[(size_t)(coe & 63) * KVOL + k];
    }
    g_pw[idx] = f2bf(v);
  }
}

// ---------------- kernel 2: gating + aux loss ----------------
__global__ __launch_bounds__(256) void k_gating(const float* __restrict__ w_gate,
                                                float* __restrict__ loss_out) {
  __shared__ float gates[BATCH][NEXP];
  __shared__ float simp[NEXP], slod[NEXP];
  const int t = threadIdx.x;
  if (t < BATCH * NEXP) (&gates[0][0])[t] = 0.f;
  __syncthreads();
  if (t < BATCH) {
    const float gi0 = g_gateinp[t * 3 + 0];
    const float gi1 = g_gateinp[t * 3 + 1];
    const float gi2 = g_gateinp[t * 3 + 2];
    float best1 = -1e30f, best2 = -1e30f;
    int i1 = 0, i2 = 0;
    for (int e = 0; e < NEXP; ++e) {
      const float lg = gi0 * w_gate[e] + gi1 * w_gate[8 + e] + gi2 * w_gate[16 + e];
      if (lg > best1) { best2 = best1; i2 = i1; best1 = lg; i1 = e; }
      else if (lg > best2) { best2 = lg; i2 = e; }
    }
    const float e21 = expf(best2 - best1);
    const float den = 1.f + e21;
    gates[t][i1] = 1.f / den;
    gates[t][i2] = e21 / den;
    float4 info;
    info.x = 1.f / den; info.y = e21 / den;
    info.z = __int_as_float(i1); info.w = __int_as_float(i2);
    g_gateinfo[t] = info;
  }
  __syncthreads();
  if (t < NEXP) {
    float si = 0.f, sl = 0.f;
    for (int b = 0; b < BATCH; ++b) {
      const float g = gates[b][t];
      si += g;
      if (g > 0.f) sl += 1.f;
    }
    simp[t] = si; slod[t] = sl;
  }
  __syncthreads();
  if (t == 0) {
    float mi = 0.f, ml = 0.f;
    for (int e = 0; e < NEXP; ++e) { mi += simp[e]; ml += slod[e]; }
    mi *= (1.f / NEXP); ml *= (1.f / NEXP);
    float vi = 0.f, vl = 0.f;
    for (int e = 0; e < NEXP; ++e) {
      const float di = simp[e] - mi; vi += di * di;
      const float dl = slod[e] - ml; vl += dl * dl;
    }
    vi *= (1.f / (NEXP - 1)); vl *= (1.f / (NEXP - 1));
    loss_out[0] = 0.01f * (vi / (mi * mi + 1e-10f) + vl / (ml * ml + 1e-10f));
  }
}

// ---------------- kernel 3: MFMA conv + LN + gated combine ----------------
// Block: 1 image x 64 pixels (2 output rows max), 4 waves, wave w = co slice.
// Phase 1: coalesced raw-window stage (f32 global -> bf16 LDS).
// Phase 2: LDS->LDS im2col rearrange. Phase 3: MFMA + LN + combine.
__global__ __launch_bounds__(256) void k_main(
    const float* __restrict__ x,
    const float* __restrict__ eB, const float* __restrict__ sB,
    const float* __restrict__ elnw, const float* __restrict__ elnb,
    const float* __restrict__ slnw, const float* __restrict__ slnb,
    float* __restrict__ out) {
  __shared__ __align__(16) ushort Plds[64 * PSTR];           // im2col (21.5 KB)
  __shared__ __align__(16) unsigned char SharedA[RAWROWS * WIN * 2]; // raw window / stats (14.8 KB)
  ushort* Raw   = reinterpret_cast<ushort*>(SharedA);
  float2* Sstats = reinterpret_cast<float2*>(SharedA);        // [wave][expert][cb][col] after MFMA

  const int tid  = threadIdx.x;
  const int lane = tid & 63;
  const int w    = tid >> 6;
  const int b    = blockIdx.x / (NPIX / 64);
  const int t    = blockIdx.x % (NPIX / 64);
  const int t64  = t * 64;
  const int ohBase = t64 / WOUT;          // pixels span oh in {ohBase, ohBase+1}

  // ---- gate info (block-uniform) ----
  const float4 gi = g_gateinfo[b];
  const float g1 = gi.x, g2 = gi.y;
  const int e1 = __builtin_amdgcn_readfirstlane(__float_as_int(gi.z));
  const int e2 = __builtin_amdgcn_readfirstlane(__float_as_int(gi.w));

  // ---- phase 1: raw window, coalesced float4 loads ----
  // row r = ci*11 + ihl, ih = ohBase*4 - 3 + ihl; 33 rows x 224 cols
  {
    const float* xb = x + (size_t)b * (CIN * HIN * WIN);
    for (int i = tid; i < RAWROWS * (WIN / 4); i += 256) {
      const int r   = i / (WIN / 4);
      const int c4  = i - r * (WIN / 4);
      const int ci  = r / 11;
      const int ihl = r - ci * 11;
      const int ih  = ohBase * 4 - 3 + ihl;
      ushort4 o;
      if ((unsigned)ih < (unsigned)HIN) {
        const float4 v = *reinterpret_cast<const float4*>(
            xb + (size_t)(ci * HIN + ih) * WIN + c4 * 4);
        o.x = f2bf(v.x); o.y = f2bf(v.y); o.z = f2bf(v.z); o.w = f2bf(v.w);
      } else {
        o.x = o.y = o.z = o.w = 0;
      }
      *reinterpret_cast<ushort4*>(&Raw[r * WIN + c4 * 4]) = o;
    }
  }

  // ---- A fragments while loads are in flight: 16-co x 3 experts x 5 K ----
  const int wbase = w * 16;
  const int arow  = wbase + (lane & 15);
  const int kcol  = (lane >> 4) * 8;
  bf16x8 afrag[3][5];
  const int eidx[3] = {e1, e2, 8};
  #pragma unroll
  for (int e = 0; e < 3; ++e) {
    #pragma unroll
    for (int ks = 0; ks < 5; ++ks) {
      const uint4 raw = *reinterpret_cast<const uint4*>(
          &g_pw[((size_t)(eidx[e] * COUT + arow)) * KPAD + ks * 32 + kcol]);
      afrag[e][ks] = __builtin_bit_cast(bf16x8, raw);
    }
  }

  __syncthreads();

  // ---- phase 2: im2col rearrange in LDS ----
  // task i -> pixel p = i/23, row r = i%23. r<21: copy 7 elems; r>=21: zero pad.
  for (int i = tid; i < 64 * 23; i += 256) {
    const int p = i / 23;
    const int r = i - p * 23;
    ushort* dst = &Plds[p * PSTR];
    if (r < 21) {
      const int ci = r / 7;
      const int kh = r - ci * 7;
      const int pg = t64 + p;
      const int oh = pg / WOUT;
      const int ow = pg - oh * WOUT;
      const int dOh = oh - ohBase;            // 0 or 1
      const int iw0 = ow * 4 - 3;             // may be -3 (left edge only)
      const ushort* src = &Raw[(ci * 11 + dOh * 4 + kh) * WIN];
      #pragma unroll
      for (int kw = 0; kw < 7; ++kw) {
        const int iw = iw0 + kw;
        const ushort v = src[iw < 0 ? 0 : iw];
        dst[r * 7 + kw] = (iw >= 0) ? v : (ushort)0;
      }
    } else {
      const int off = KVOL + (r - 21) * 7;    // 147..153, 154..160 (< PSTR)
      #pragma unroll
      for (int j = 0; j < 7; ++j) dst[off + j] = 0;
    }
  }

  __syncthreads();

  // ---- phase 3: MFMA  acc[cb][e] = W_e · P ----
  f32x4 acc[4][3];
  #pragma unroll
  for (int cb = 0; cb < 4; ++cb)
    #pragma unroll
    for (int e = 0; e < 3; ++e) acc[cb][e] = (f32x4){0.f, 0.f, 0.f, 0.f};

  #pragma unroll
  for (int cb = 0; cb < 4; ++cb) {
    bf16x8 bfrag[5];
    #pragma unroll
    for (int ks = 0; ks < 5; ++ks) {
      const uint4 raw = *reinterpret_cast<const uint4*>(
          &Plds[(cb * 16 + (lane & 15)) * PSTR + ks * 32 + kcol]);
      bfrag[ks] = __builtin_bit_cast(bf16x8, raw);
    }
    #pragma unroll
    for (int ks = 0; ks < 5; ++ks)
      #pragma unroll
      for (int e = 0; e < 3; ++e)
        acc[cb][e] = __builtin_amdgcn_mfma_f32_16x16x32_bf16(
            afrag[e][ks], bfrag[ks], acc[cb][e], 0, 0, 0);
  }

  // ---- bias + per-pixel LN stats ----
  const int co0 = wbase + (lane >> 4) * 4;
  const int col = lane & 15;
  float4 bias[3];
  bias[0] = *reinterpret_cast<const float4*>(eB + e1 * COUT + co0);
  bias[1] = *reinterpret_cast<const float4*>(eB + e2 * COUT + co0);
  bias[2] = *reinterpret_cast<const float4*>(sB + co0);
  #pragma unroll
  for (int cb = 0; cb < 4; ++cb)
    #pragma unroll
    for (int e = 0; e < 3; ++e) {
      acc[cb][e][0] += (&bias[e].x)[0];
      acc[cb][e][1] += (&bias[e].x)[1];
      acc[cb][e][2] += (&bias[e].x)[2];
      acc[cb][e][3] += (&bias[e].x)[3];
    }

  #pragma unroll
  for (int cb = 0; cb < 4; ++cb)
    #pragma unroll
    for (int e = 0; e < 3; ++e) {
      float s = acc[cb][e][0] + acc[cb][e][1] + acc[cb][e][2] + acc[cb][e][3];
      float q = acc[cb][e][0] * acc[cb][e][0] + acc[cb][e][1] * acc[cb][e][1]
              + acc[cb][e][2] * acc[cb][e][2] + acc[cb][e][3] * acc[cb][e][3];
      s += __shfl_xor(s, 16, 64); s += __shfl_xor(s, 32, 64);
      q += __shfl_xor(q, 16, 64); q += __shfl_xor(q, 32, 64);
      if (lane < 16) Sstats[((w * 3 + e) * 4 + cb) * 16 + col] = make_float2(s, q);
    }
  __syncthreads();

  // ---- LN + gated combine + store ----
  float4 lw[3], lb[3];
  lw[0] = *reinterpret_cast<const float4*>(elnw + e1 * COUT + co0);
  lw[1] = *reinterpret_cast<const float4*>(elnw + e2 * COUT + co0);
  lw[2] = *reinterpret_cast<const float4*>(slnw + co0);
  lb[0] = *reinterpret_cast<const float4*>(elnb + e1 * COUT + co0);
  lb[1] = *reinterpret_cast<const float4*>(elnb + e2 * COUT + co0);
  lb[2] = *reinterpret_cast<const float4*>(slnb + co0);
  const float ge[3] = {g1, g2, 1.f};

  float* outb = out + (size_t)b * (COUT * NPIX) + t64;
  #pragma unroll
  for (int cb = 0; cb < 4; ++cb) {
    float u[3], rr[3];
    #pragma unroll
    for (int e = 0; e < 3; ++e) {
      float s = 0.f, q = 0.f;
      #pragma unroll
      for (int ww = 0; ww < 4; ++ww) {
        const float2 sq = Sstats[((ww * 3 + e) * 4 + cb) * 16 + col];
        s += sq.x; q += sq.y;
      }
      u[e] = s * (1.f / 64.f);
      const float var = q * (1.f / 64.f) - u[e] * u[e];
      rr[e] = rsqrtf(var + LN_EPS_F);
    }
    #pragma unroll
    for (int reg = 0; reg < 4; ++reg) {
      float o = 0.f;
      #pragma unroll
      for (int e = 0; e < 3; ++e) {
        const float y = acc[cb][e][reg];
        o += ge[e] * ((&lw[e].x)[reg] * (y - u[e]) * rr[e] + (&lb[e].x)[reg]);
      }
      outb[(size_t)(co0 + reg) * NPIX + cb * 16 + col] = o;
    }
  }
}

// ---------------- launch ----------------
extern "C" void kernel_launch(void* const* d_in, const int* in_sizes, int n_in,
                              void* d_out, int out_size, void* d_ws, size_t ws_size,
                              hipStream_t stream) {
  const float* x    = (const float*)d_in[0];
  const float* eW   = (const float*)d_in[1];
  const float* eB   = (const float*)d_in[2];
  const float* elnw = (const float*)d_in[3];
  const float* elnb = (const float*)d_in[4];
  const float* sW   = (const float*)d_in[5];
  const float* sB   = (const float*)d_in[6];
  const float* slnw = (const float*)d_in[7];
  const float* slnb = (const float*)d_in[8];
  const float* wg   = (const float*)d_in[9];
  float* out = (float*)d_out;

  float* loss_ptr = out + (size_t)BATCH * COUT * NPIX;

  const int repack_blocks = (9 * COUT * KPAD + 255) / 256;   // 360
  k_pre<<<BATCH * CIN + repack_blocks, 256, 0, stream>>>(x, eW, sW);
  k_gating<<<1, 256, 0, stream>>>(wg, loss_ptr);
  k_main<<<BATCH * (NPIX / 64), 256, 0, stream>>>(x, eB, sB, elnw, elnb,
                                                  slnw, slnb, out);
}